// Round 2
// baseline (2022.416 us; speedup 1.0000x reference)
//
#include <hip/hip_runtime.h>

// Problem constants (fixed by the reference setup_inputs).
static constexpr int NN = 100000;   // nodes
static constexpr int NE = 3200000;  // edges

// ---------------- degree / normalization ----------------

__global__ void k_init_deg(float* __restrict__ deg, int n) {
    int i = blockIdx.x * blockDim.x + threadIdx.x;
    if (i < n) deg[i] = 1.0f;  // self-loop
}

__global__ void k_deg_count(const int* __restrict__ dst, float* __restrict__ deg, int e) {
    int i = blockIdx.x * blockDim.x + threadIdx.x;
    if (i < e) atomicAdd(&deg[dst[i]], 1.0f);
}

__global__ void k_rsqrt_inplace(float* __restrict__ d, int n) {
    int i = blockIdx.x * blockDim.x + threadIdx.x;
    if (i < n) d[i] = rsqrtf(d[i]);
}

// ---------------- layer 1 transform: g1[i][f] = (x[i] @ W1)[f] * dinv[i] ----------------
// 8 threads per node, 4 features each (float4 store). W1 is (3,32) row-major.

__global__ void k_xform1(const float* __restrict__ x, const float* __restrict__ W1,
                         const float* __restrict__ dinv, float4* __restrict__ g1, int n) {
    __shared__ float Ws[96];
    int tid = threadIdx.x;
    if (tid < 96) Ws[tid] = W1[tid];
    __syncthreads();
    int node = blockIdx.x * 32 + (tid >> 3);
    if (node >= n) return;
    int f = (tid & 7) * 4;
    float x0 = x[node * 3 + 0], x1 = x[node * 3 + 1], x2 = x[node * 3 + 2];
    float di = dinv[node];
    float4 o;
    o.x = (x0 * Ws[f + 0] + x1 * Ws[32 + f + 0] + x2 * Ws[64 + f + 0]) * di;
    o.y = (x0 * Ws[f + 1] + x1 * Ws[32 + f + 1] + x2 * Ws[64 + f + 1]) * di;
    o.z = (x0 * Ws[f + 2] + x1 * Ws[32 + f + 2] + x2 * Ws[64 + f + 2]) * di;
    o.w = (x0 * Ws[f + 3] + x1 * Ws[32 + f + 3] + x2 * Ws[64 + f + 3]) * di;
    g1[node * 8 + (tid & 7)] = o;
}

// ---------------- edge aggregation, layer 1 (32 features) ----------------
// 8 threads per edge; each does a float4 gather from g1[src] and 4 atomic adds into acc1[dst].

__global__ void k_edge_agg32(const int* __restrict__ src, const int* __restrict__ dst,
                             const float4* __restrict__ g1, float* __restrict__ acc1, int e) {
    int t = blockIdx.x * blockDim.x + threadIdx.x;
    if (t >= e * 8) return;
    int edge = t >> 3, f4 = t & 7;
    int s = src[edge];
    int d = dst[edge];
    float4 v = g1[s * 8 + f4];
    float* a = acc1 + d * 32 + f4 * 4;
    atomicAdd(a + 0, v.x);
    atomicAdd(a + 1, v.y);
    atomicAdd(a + 2, v.z);
    atomicAdd(a + 3, v.w);
}

// ---------------- mid node pass: h2 = relu(dinv*(acc1+g1)+b1); g2 = (h2 @ W2)*dinv ----------------
// W2 is (32,3) row-major.

__global__ void k_mid(const float4* __restrict__ acc1, const float4* __restrict__ g1,
                      const float* __restrict__ dinv, const float* __restrict__ b1,
                      const float* __restrict__ W2, float* __restrict__ g2, int n) {
    __shared__ float W2s[96];
    __shared__ float b1s[32];
    int tid = threadIdx.x;
    if (tid < 96) W2s[tid] = W2[tid];
    if (tid < 32) b1s[tid] = b1[tid];
    __syncthreads();
    int i = blockIdx.x * blockDim.x + tid;
    if (i >= n) return;
    float di = dinv[i];
    float p0 = 0.f, p1 = 0.f, p2 = 0.f;
#pragma unroll
    for (int q = 0; q < 8; ++q) {
        float4 a = acc1[i * 8 + q];
        float4 g = g1[i * 8 + q];
        float av[4] = {a.x, a.y, a.z, a.w};
        float gv[4] = {g.x, g.y, g.z, g.w};
#pragma unroll
        for (int j = 0; j < 4; ++j) {
            int f = q * 4 + j;
            float h = fmaxf(di * (av[j] + gv[j]) + b1s[f], 0.f);
            p0 += h * W2s[f * 3 + 0];
            p1 += h * W2s[f * 3 + 1];
            p2 += h * W2s[f * 3 + 2];
        }
    }
    g2[i * 3 + 0] = p0 * di;
    g2[i * 3 + 1] = p1 * di;
    g2[i * 3 + 2] = p2 * di;
}

// ---------------- edge aggregation, layer 2 (3 features) ----------------

__global__ void k_edge_agg3(const int* __restrict__ src, const int* __restrict__ dst,
                            const float* __restrict__ g2, float* __restrict__ acc2, int e) {
    int i = blockIdx.x * blockDim.x + threadIdx.x;
    if (i >= e) return;
    int s = src[i];
    int d = dst[i];
    atomicAdd(&acc2[d * 3 + 0], g2[s * 3 + 0]);
    atomicAdd(&acc2[d * 3 + 1], g2[s * 3 + 1]);
    atomicAdd(&acc2[d * 3 + 2], g2[s * 3 + 2]);
}

// ---------------- final: out = dinv*(acc2+g2) + b2 ----------------

__global__ void k_final(const float* __restrict__ acc2, const float* __restrict__ g2,
                        const float* __restrict__ dinv, const float* __restrict__ b2,
                        float* __restrict__ out, int n3) {
    int t = blockIdx.x * blockDim.x + threadIdx.x;
    if (t >= n3) return;
    int i = t / 3;
    int c = t - i * 3;
    out[t] = dinv[i] * (acc2[t] + g2[t]) + b2[c];
}

extern "C" void kernel_launch(void* const* d_in, const int* in_sizes, int n_in,
                              void* d_out, int out_size, void* d_ws, size_t ws_size,
                              hipStream_t stream) {
    const float* x   = (const float*)d_in[0];  // [N,3]
    const int* ei    = (const int*)d_in[1];    // [2,E] as int32: src = ei[0:E], dst = ei[E:2E]
    const float* W1  = (const float*)d_in[2];  // [3,32]
    const float* b1  = (const float*)d_in[3];  // [32]
    const float* W2  = (const float*)d_in[4];  // [32,3]
    const float* b2  = (const float*)d_in[5];  // [3]
    float* out       = (float*)d_out;          // [N,3]

    const int n = NN, e = NE;
    const int* src = ei;
    const int* dst = ei + e;

    float* ws   = (float*)d_ws;
    // Workspace layout (floats): dinv[n] | g1[32n] | g2[3n] | acc1[32n] | acc2[3n]  (71n total)
    float* dinv = ws;
    float* g1   = ws + (size_t)n;
    float* g2   = ws + (size_t)33 * n;
    float* acc1 = ws + (size_t)36 * n;
    float* acc2 = ws + (size_t)68 * n;

    // Zero the two accumulators in one contiguous memset (ws is poisoned each call).
    hipMemsetAsync(acc1, 0, (size_t)35 * n * sizeof(float), stream);

    k_init_deg<<<(n + 255) / 256, 256, 0, stream>>>(dinv, n);
    k_deg_count<<<(e + 255) / 256, 256, 0, stream>>>(dst, dinv, e);
    k_rsqrt_inplace<<<(n + 255) / 256, 256, 0, stream>>>(dinv, n);

    k_xform1<<<(n + 31) / 32, 256, 0, stream>>>(x, W1, dinv, (float4*)g1, n);
    k_edge_agg32<<<(e * 8 + 255) / 256, 256, 0, stream>>>(src, dst, (const float4*)g1, acc1, e);
    k_mid<<<(n + 255) / 256, 256, 0, stream>>>((const float4*)acc1, (const float4*)g1,
                                               dinv, b1, W2, g2, n);
    k_edge_agg3<<<(e + 255) / 256, 256, 0, stream>>>(src, dst, g2, acc2, e);
    k_final<<<(3 * n + 255) / 256, 256, 0, stream>>>(acc2, g2, dinv, b2, out, 3 * n);
}

// Round 3
// 625.360 us; speedup vs baseline: 3.2340x; 3.2340x over previous
//
#include <hip/hip_runtime.h>

// Problem constants (fixed by the reference setup_inputs).
static constexpr int NN = 100000;   // nodes
static constexpr int NE = 3200000;  // edges
static constexpr int SCAN_B = 256;                          // elems per scan block
static constexpr int NB = (NN + SCAN_B - 1) / SCAN_B;       // 391 scan blocks

// ---------------- degree count (deg stored as float in dinv buffer, zeroed by memset) ----------------

__global__ void k_deg_count(const int* __restrict__ dst, float* __restrict__ deg, int e) {
    int i = blockIdx.x * blockDim.x + threadIdx.x;
    if (i < e) atomicAdd(&deg[dst[i]], 1.0f);
}

// ---------------- scan step 1: per-block sums of deg ----------------

__global__ void k_scan1(const float* __restrict__ deg, int* __restrict__ bsum, int n) {
    __shared__ int s[SCAN_B];
    int t = threadIdx.x;
    int i = blockIdx.x * SCAN_B + t;
    s[t] = (i < n) ? (int)deg[i] : 0;
    __syncthreads();
    for (int off = SCAN_B / 2; off > 0; off >>= 1) {
        if (t < off) s[t] += s[t + off];
        __syncthreads();
    }
    if (t == 0) bsum[blockIdx.x] = s[0];
}

// ---------------- scan step 2: exclusive scan of block sums (single block of 512) ----------------

__global__ void k_scan2(const int* __restrict__ bsum, int* __restrict__ bpre, int nb) {
    __shared__ int s[512];
    int t = threadIdx.x;
    int v = (t < nb) ? bsum[t] : 0;
    s[t] = v;
    __syncthreads();
    for (int off = 1; off < 512; off <<= 1) {
        int add = (t >= off) ? s[t - off] : 0;
        __syncthreads();
        s[t] += add;
        __syncthreads();
    }
    if (t < nb) bpre[t] = s[t] - v;  // exclusive
}

// ---------------- scan step 3: per-block exclusive scan -> rowptr, cursor; dinv finalize ----------------

__global__ void k_scan3(float* __restrict__ dinv, const int* __restrict__ bpre,
                        int* __restrict__ rowptr, int* __restrict__ cursor, int n) {
    __shared__ int s[SCAN_B];
    int t = threadIdx.x;
    int i = blockIdx.x * SCAN_B + t;
    float degf = (i < n) ? dinv[i] : 0.0f;
    int d = (int)degf;
    s[t] = d;
    __syncthreads();
    for (int off = 1; off < SCAN_B; off <<= 1) {
        int add = (t >= off) ? s[t - off] : 0;
        __syncthreads();
        s[t] += add;
        __syncthreads();
    }
    if (i < n) {
        int rp = bpre[blockIdx.x] + s[t] - d;  // exclusive prefix
        rowptr[i] = rp;
        cursor[i] = rp;
        dinv[i] = rsqrtf(degf + 1.0f);  // +1 self-loop
    }
}

// ---------------- scatter edges into CSR (sorted by dst) ----------------

__global__ void k_scatter(const int* __restrict__ src, const int* __restrict__ dst,
                          int* __restrict__ cursor, int* __restrict__ csr_src, int e) {
    int i = blockIdx.x * blockDim.x + threadIdx.x;
    if (i >= e) return;
    int d = dst[i];
    int pos = atomicAdd(&cursor[d], 1);
    csr_src[pos] = src[i];
}

// ---------------- layer 1 transform: g1[i][f] = (x[i] @ W1)[f] * dinv[i] ----------------

__global__ void k_xform1(const float* __restrict__ x, const float* __restrict__ W1,
                         const float* __restrict__ dinv, float4* __restrict__ g1, int n) {
    __shared__ float Ws[96];
    int tid = threadIdx.x;
    if (tid < 96) Ws[tid] = W1[tid];
    __syncthreads();
    int node = blockIdx.x * 32 + (tid >> 3);
    if (node >= n) return;
    int f = (tid & 7) * 4;
    float x0 = x[node * 3 + 0], x1 = x[node * 3 + 1], x2 = x[node * 3 + 2];
    float di = dinv[node];
    float4 o;
    o.x = (x0 * Ws[f + 0] + x1 * Ws[32 + f + 0] + x2 * Ws[64 + f + 0]) * di;
    o.y = (x0 * Ws[f + 1] + x1 * Ws[32 + f + 1] + x2 * Ws[64 + f + 1]) * di;
    o.z = (x0 * Ws[f + 2] + x1 * Ws[32 + f + 2] + x2 * Ws[64 + f + 2]) * di;
    o.w = (x0 * Ws[f + 3] + x1 * Ws[32 + f + 3] + x2 * Ws[64 + f + 3]) * di;
    g1[node * 8 + (tid & 7)] = o;
}

// ---------------- fused layer-1 aggregation + mid node pass ----------------
// One wave per node. Lane = slot*8 + chunk: 8 edge slots x 8 float4 chunks.
// agg = sum_{in-edges} g1[src]; h2 = relu(dinv*(agg + g1[self]) + b1); g2 = (h2 @ W2) * dinv.

__global__ void k_agg32_mid(const int* __restrict__ rowptr, const int* __restrict__ rowend,
                            const int* __restrict__ csr_src, const float4* __restrict__ g1,
                            const float* __restrict__ dinv, const float* __restrict__ b1,
                            const float* __restrict__ W2, float* __restrict__ g2, int n) {
    __shared__ float W2s[96];
    __shared__ float b1s[32];
    int tid = threadIdx.x;
    if (tid < 96) W2s[tid] = W2[tid];
    if (tid < 32) b1s[tid] = b1[tid];
    __syncthreads();

    int node = blockIdx.x * 4 + (tid >> 6);
    if (node >= n) return;
    int lane = tid & 63;
    int chunk = lane & 7;   // which float4 of the 32 features
    int slot = lane >> 3;   // which edge within a group of 8

    int beg = rowptr[node];
    int end = rowend[node];

    float4 acc = make_float4(0.f, 0.f, 0.f, 0.f);
    for (int i = beg + slot; i < end; i += 8) {
        int s = csr_src[i];
        float4 v = g1[s * 8 + chunk];
        acc.x += v.x; acc.y += v.y; acc.z += v.z; acc.w += v.w;
    }
    // reduce across the 8 slots (lane offsets 32, 16, 8)
    for (int off = 32; off >= 8; off >>= 1) {
        acc.x += __shfl_down(acc.x, off, 64);
        acc.y += __shfl_down(acc.y, off, 64);
        acc.z += __shfl_down(acc.z, off, 64);
        acc.w += __shfl_down(acc.w, off, 64);
    }

    float di = dinv[node];
    float p0 = 0.f, p1 = 0.f, p2 = 0.f;
    if (slot == 0) {  // lanes 0..7 hold the 8 chunk sums
        float4 gs = g1[node * 8 + chunk];  // self-loop term (already * dinv[node])
        float av[4] = {acc.x + gs.x, acc.y + gs.y, acc.z + gs.z, acc.w + gs.w};
#pragma unroll
        for (int j = 0; j < 4; ++j) {
            int f = chunk * 4 + j;
            float h = fmaxf(di * av[j] + b1s[f], 0.f);
            p0 += h * W2s[f * 3 + 0];
            p1 += h * W2s[f * 3 + 1];
            p2 += h * W2s[f * 3 + 2];
        }
    }
    // reduce the partial dot products across lanes 0..7
    for (int off = 4; off >= 1; off >>= 1) {
        p0 += __shfl_down(p0, off, 64);
        p1 += __shfl_down(p1, off, 64);
        p2 += __shfl_down(p2, off, 64);
    }
    if (lane == 0) {
        g2[node * 3 + 0] = p0 * di;
        g2[node * 3 + 1] = p1 * di;
        g2[node * 3 + 2] = p2 * di;
    }
}

// ---------------- fused layer-2 aggregation + final ----------------
// One wave per node, lane per edge. out = dinv*(agg + g2[self]) + b2.

__global__ void k_agg3_final(const int* __restrict__ rowptr, const int* __restrict__ rowend,
                             const int* __restrict__ csr_src, const float* __restrict__ g2,
                             const float* __restrict__ dinv, const float* __restrict__ b2,
                             float* __restrict__ out, int n) {
    int tid = threadIdx.x;
    int node = blockIdx.x * 4 + (tid >> 6);
    if (node >= n) return;
    int lane = tid & 63;

    int beg = rowptr[node];
    int end = rowend[node];

    float a0 = 0.f, a1 = 0.f, a2 = 0.f;
    for (int i = beg + lane; i < end; i += 64) {
        int s = csr_src[i];
        a0 += g2[s * 3 + 0];
        a1 += g2[s * 3 + 1];
        a2 += g2[s * 3 + 2];
    }
    for (int off = 32; off >= 1; off >>= 1) {
        a0 += __shfl_down(a0, off, 64);
        a1 += __shfl_down(a1, off, 64);
        a2 += __shfl_down(a2, off, 64);
    }
    if (lane == 0) {
        float di = dinv[node];
        out[node * 3 + 0] = di * (a0 + g2[node * 3 + 0]) + b2[0];
        out[node * 3 + 1] = di * (a1 + g2[node * 3 + 1]) + b2[1];
        out[node * 3 + 2] = di * (a2 + g2[node * 3 + 2]) + b2[2];
    }
}

extern "C" void kernel_launch(void* const* d_in, const int* in_sizes, int n_in,
                              void* d_out, int out_size, void* d_ws, size_t ws_size,
                              hipStream_t stream) {
    const float* x   = (const float*)d_in[0];  // [N,3]
    const int* ei    = (const int*)d_in[1];    // [2,E] int32: src = ei[0:E], dst = ei[E:2E]
    const float* W1  = (const float*)d_in[2];  // [3,32]
    const float* b1  = (const float*)d_in[3];  // [32]
    const float* W2  = (const float*)d_in[4];  // [32,3]
    const float* b2  = (const float*)d_in[5];  // [3]
    float* out       = (float*)d_out;          // [N,3]

    const int n = NN, e = NE;
    const int* src = ei;
    const int* dst = ei + e;

    // Workspace layout (4-byte elems):
    //   dinv[n] (holds fp degree during counting) | g1[32n] | g2[3n] |
    //   rowptr[n] | cursor[n] | csr_src[E] | bsum[NB] | bpre[NB]
    float* ws     = (float*)d_ws;
    float* dinv   = ws;
    float* g1     = ws + (size_t)n;
    float* g2     = ws + (size_t)33 * n;
    int* rowptr   = (int*)(ws + (size_t)36 * n);
    int* cursor   = rowptr + n;
    int* csr_src  = cursor + n;
    int* bsum     = csr_src + e;
    int* bpre     = bsum + NB;

    // Zero the degree buffer only (400 KB).
    hipMemsetAsync(dinv, 0, (size_t)n * sizeof(float), stream);

    k_deg_count<<<(e + 255) / 256, 256, 0, stream>>>(dst, dinv, e);
    k_scan1<<<NB, SCAN_B, 0, stream>>>(dinv, bsum, n);
    k_scan2<<<1, 512, 0, stream>>>(bsum, bpre, NB);
    k_scan3<<<NB, SCAN_B, 0, stream>>>(dinv, bpre, rowptr, cursor, n);
    k_scatter<<<(e + 255) / 256, 256, 0, stream>>>(src, dst, cursor, csr_src, e);
    // after k_scatter, cursor[i] == end of node i's edge range

    k_xform1<<<(n + 31) / 32, 256, 0, stream>>>(x, W1, dinv, (float4*)g1, n);
    k_agg32_mid<<<(n + 3) / 4, 256, 0, stream>>>(rowptr, cursor, csr_src, (const float4*)g1,
                                                 dinv, b1, W2, g2, n);
    k_agg3_final<<<(n + 3) / 4, 256, 0, stream>>>(rowptr, cursor, csr_src, g2, dinv, b2, out, n);
}

// Round 4
// 263.775 us; speedup vs baseline: 7.6672x; 2.3708x over previous
//
#include <hip/hip_runtime.h>

// Problem constants (fixed by the reference setup_inputs).
static constexpr int NN = 100000;   // nodes
static constexpr int NE = 3200000;  // edges

// Bucketed counting-sort parameters.
static constexpr int BKT_SHIFT = 9;                       // 512 nodes per bucket
static constexpr int BKT_NODES = 1 << BKT_SHIFT;          // 512
static constexpr int NBUCK = (NN + BKT_NODES - 1) >> BKT_SHIFT;  // 196
static constexpr int P1_BLOCKS = 256;
static constexpr int EPB = NE / P1_BLOCKS;                // 12500 edges per phase-1 block (exact)
static constexpr int EPT = (EPB + 255) / 256;             // 49 edges per thread
static constexpr int HTOT = NBUCK * P1_BLOCKS;            // 50176 histogram cells
static constexpr int H2_T = 1024;
static constexpr int H2_C = HTOT / H2_T;                  // 49 (exact)

// ---------------- phase 1a: per-block bucket histograms (LDS, no global atomics) ----------------

__global__ void k_hist(const int* __restrict__ dst, int* __restrict__ bh) {
    __shared__ int hist[256];
    int t = threadIdx.x, blk = blockIdx.x;
    hist[t] = 0;
    __syncthreads();
    int base = blk * EPB;
#pragma unroll
    for (int j = 0; j < EPT; ++j) {
        int o = j * 256 + t;
        if (o < EPB) atomicAdd(&hist[dst[base + o] >> BKT_SHIFT], 1);
    }
    __syncthreads();
    if (t < NBUCK) bh[t * P1_BLOCKS + blk] = hist[t];  // bucket-major
}

// ---------------- phase 1b: exclusive scan of all 50176 cells, in place (single block) --------

__global__ void k_hscan(int* __restrict__ bh) {
    __shared__ int s[H2_T];
    int t = threadIdx.x;
    int base = t * H2_C;
    int sum = 0;
#pragma unroll
    for (int j = 0; j < H2_C; ++j) sum += bh[base + j];
    s[t] = sum;
    __syncthreads();
    for (int off = 1; off < H2_T; off <<= 1) {
        int add = (t >= off) ? s[t - off] : 0;
        __syncthreads();
        s[t] += add;
        __syncthreads();
    }
    int run = s[t] - sum;  // exclusive prefix of this thread's chunk
#pragma unroll
    for (int j = 0; j < H2_C; ++j) {
        int v = bh[base + j];
        bh[base + j] = run;
        run += v;
    }
}

// ---------------- phase 1c: scatter packed (src,dlocal) keys into bucket order ----------------

__global__ void k_bucket(const int* __restrict__ src, const int* __restrict__ dst,
                         const int* __restrict__ bh, int* __restrict__ keys) {
    __shared__ int cur[256];
    int t = threadIdx.x, blk = blockIdx.x;
    if (t < NBUCK) cur[t] = bh[t * P1_BLOCKS + blk];
    __syncthreads();
    int base = blk * EPB;
#pragma unroll
    for (int j = 0; j < EPT; ++j) {
        int o = j * 256 + t;
        if (o < EPB) {
            int d = dst[base + o];
            int b = d >> BKT_SHIFT;
            int pos = atomicAdd(&cur[b], 1);  // LDS atomic only
            keys[pos] = (src[base + o] << BKT_SHIFT) | (d & (BKT_NODES - 1));
        }
    }
}

// ---------------- phase 2: per-bucket exact CSR + rowptr/rowend/dinv (LDS only) ---------------

__global__ void k_csr(const int* __restrict__ keys, const int* __restrict__ bh,
                      int* __restrict__ csr_src, int* __restrict__ rowptr,
                      int* __restrict__ rowend, float* __restrict__ dinv, int n) {
    __shared__ int cnt[BKT_NODES];
    __shared__ int s[BKT_NODES];
    __shared__ int cur[BKT_NODES];
    int t = threadIdx.x, b = blockIdx.x;
    int bstart = bh[b * P1_BLOCKS];
    int bend = (b + 1 < NBUCK) ? bh[(b + 1) * P1_BLOCKS] : NE;
    cnt[t] = 0;
    __syncthreads();
    for (int i = bstart + t; i < bend; i += BKT_NODES)
        atomicAdd(&cnt[keys[i] & (BKT_NODES - 1)], 1);
    __syncthreads();
    int c = cnt[t];
    s[t] = c;
    __syncthreads();
    for (int off = 1; off < BKT_NODES; off <<= 1) {
        int add = (t >= off) ? s[t - off] : 0;
        __syncthreads();
        s[t] += add;
        __syncthreads();
    }
    int rp = bstart + s[t] - c;  // exclusive
    cur[t] = rp;
    int node = b * BKT_NODES + t;
    if (node < n) {
        rowptr[node] = rp;
        rowend[node] = rp + c;
        dinv[node] = rsqrtf((float)c + 1.0f);  // +1 self-loop
    }
    __syncthreads();
    for (int i = bstart + t; i < bend; i += BKT_NODES) {
        int k = keys[i];
        int pos = atomicAdd(&cur[k & (BKT_NODES - 1)], 1);  // LDS atomic only
        csr_src[pos] = ((unsigned)k) >> BKT_SHIFT;
    }
}

// ---------------- layer 1 transform: g1[i][f] = (x[i] @ W1)[f] * dinv[i] ----------------

__global__ void k_xform1(const float* __restrict__ x, const float* __restrict__ W1,
                         const float* __restrict__ dinv, float4* __restrict__ g1, int n) {
    __shared__ float Ws[96];
    int tid = threadIdx.x;
    if (tid < 96) Ws[tid] = W1[tid];
    __syncthreads();
    int node = blockIdx.x * 32 + (tid >> 3);
    if (node >= n) return;
    int f = (tid & 7) * 4;
    float x0 = x[node * 3 + 0], x1 = x[node * 3 + 1], x2 = x[node * 3 + 2];
    float di = dinv[node];
    float4 o;
    o.x = (x0 * Ws[f + 0] + x1 * Ws[32 + f + 0] + x2 * Ws[64 + f + 0]) * di;
    o.y = (x0 * Ws[f + 1] + x1 * Ws[32 + f + 1] + x2 * Ws[64 + f + 1]) * di;
    o.z = (x0 * Ws[f + 2] + x1 * Ws[32 + f + 2] + x2 * Ws[64 + f + 2]) * di;
    o.w = (x0 * Ws[f + 3] + x1 * Ws[32 + f + 3] + x2 * Ws[64 + f + 3]) * di;
    g1[node * 8 + (tid & 7)] = o;
}

// ---------------- fused layer-1 aggregation + mid node pass ----------------
// One wave per node. Lane = slot*8 + chunk: 8 edge slots x 8 float4 chunks.

__global__ void k_agg32_mid(const int* __restrict__ rowptr, const int* __restrict__ rowend,
                            const int* __restrict__ csr_src, const float4* __restrict__ g1,
                            const float* __restrict__ dinv, const float* __restrict__ b1,
                            const float* __restrict__ W2, float* __restrict__ g2, int n) {
    __shared__ float W2s[96];
    __shared__ float b1s[32];
    int tid = threadIdx.x;
    if (tid < 96) W2s[tid] = W2[tid];
    if (tid < 32) b1s[tid] = b1[tid];
    __syncthreads();

    int node = blockIdx.x * 4 + (tid >> 6);
    if (node >= n) return;
    int lane = tid & 63;
    int chunk = lane & 7;
    int slot = lane >> 3;

    int beg = rowptr[node];
    int end = rowend[node];

    float4 acc = make_float4(0.f, 0.f, 0.f, 0.f);
    for (int i = beg + slot; i < end; i += 8) {
        int s = csr_src[i];
        float4 v = g1[s * 8 + chunk];
        acc.x += v.x; acc.y += v.y; acc.z += v.z; acc.w += v.w;
    }
    for (int off = 32; off >= 8; off >>= 1) {
        acc.x += __shfl_down(acc.x, off, 64);
        acc.y += __shfl_down(acc.y, off, 64);
        acc.z += __shfl_down(acc.z, off, 64);
        acc.w += __shfl_down(acc.w, off, 64);
    }

    float di = dinv[node];
    float p0 = 0.f, p1 = 0.f, p2 = 0.f;
    if (slot == 0) {
        float4 gs = g1[node * 8 + chunk];  // self-loop term (already * dinv[node])
        float av[4] = {acc.x + gs.x, acc.y + gs.y, acc.z + gs.z, acc.w + gs.w};
#pragma unroll
        for (int j = 0; j < 4; ++j) {
            int f = chunk * 4 + j;
            float h = fmaxf(di * av[j] + b1s[f], 0.f);
            p0 += h * W2s[f * 3 + 0];
            p1 += h * W2s[f * 3 + 1];
            p2 += h * W2s[f * 3 + 2];
        }
    }
    for (int off = 4; off >= 1; off >>= 1) {
        p0 += __shfl_down(p0, off, 64);
        p1 += __shfl_down(p1, off, 64);
        p2 += __shfl_down(p2, off, 64);
    }
    if (lane == 0) {
        g2[node * 3 + 0] = p0 * di;
        g2[node * 3 + 1] = p1 * di;
        g2[node * 3 + 2] = p2 * di;
    }
}

// ---------------- fused layer-2 aggregation + final ----------------

__global__ void k_agg3_final(const int* __restrict__ rowptr, const int* __restrict__ rowend,
                             const int* __restrict__ csr_src, const float* __restrict__ g2,
                             const float* __restrict__ dinv, const float* __restrict__ b2,
                             float* __restrict__ out, int n) {
    int tid = threadIdx.x;
    int node = blockIdx.x * 4 + (tid >> 6);
    if (node >= n) return;
    int lane = tid & 63;

    int beg = rowptr[node];
    int end = rowend[node];

    float a0 = 0.f, a1 = 0.f, a2 = 0.f;
    for (int i = beg + lane; i < end; i += 64) {
        int s = csr_src[i];
        a0 += g2[s * 3 + 0];
        a1 += g2[s * 3 + 1];
        a2 += g2[s * 3 + 2];
    }
    for (int off = 32; off >= 1; off >>= 1) {
        a0 += __shfl_down(a0, off, 64);
        a1 += __shfl_down(a1, off, 64);
        a2 += __shfl_down(a2, off, 64);
    }
    if (lane == 0) {
        float di = dinv[node];
        out[node * 3 + 0] = di * (a0 + g2[node * 3 + 0]) + b2[0];
        out[node * 3 + 1] = di * (a1 + g2[node * 3 + 1]) + b2[1];
        out[node * 3 + 2] = di * (a2 + g2[node * 3 + 2]) + b2[2];
    }
}

extern "C" void kernel_launch(void* const* d_in, const int* in_sizes, int n_in,
                              void* d_out, int out_size, void* d_ws, size_t ws_size,
                              hipStream_t stream) {
    const float* x   = (const float*)d_in[0];  // [N,3]
    const int* ei    = (const int*)d_in[1];    // [2,E] int32: src = ei[0:E], dst = ei[E:2E]
    const float* W1  = (const float*)d_in[2];  // [3,32]
    const float* b1  = (const float*)d_in[3];  // [32]
    const float* W2  = (const float*)d_in[4];  // [32,3]
    const float* b2  = (const float*)d_in[5];  // [3]
    float* out       = (float*)d_out;          // [N,3]

    const int n = NN;
    const int* src = ei;
    const int* dst = ei + NE;

    // Workspace layout (4-byte units):
    //   [0]            keys (NE ints) during build, then g1 (32n floats == NE) — exact overlap
    //   [NE]           csr_src (NE ints)
    //   [2*NE]         dinv (n) | rowptr (n) | rowend (n) | g2 (3n) | bh (HTOT)
    int* wsi      = (int*)d_ws;
    int* keys     = wsi;                       // phase-1 output, dead after k_csr
    float* g1     = (float*)wsi;               // aliases keys; written by k_xform1 after k_csr
    int* csr_src  = wsi + (size_t)NE;
    float* dinv   = (float*)(wsi + (size_t)2 * NE);
    int* rowptr   = (int*)(dinv + n);
    int* rowend   = rowptr + n;
    float* g2     = (float*)(rowend + n);
    int* bh       = (int*)(g2 + (size_t)3 * n);

    // ---- atomic-free CSR build ----
    k_hist<<<P1_BLOCKS, 256, 0, stream>>>(dst, bh);
    k_hscan<<<1, H2_T, 0, stream>>>(bh);
    k_bucket<<<P1_BLOCKS, 256, 0, stream>>>(src, dst, bh, keys);
    k_csr<<<NBUCK, BKT_NODES, 0, stream>>>(keys, bh, csr_src, rowptr, rowend, dinv, n);

    // ---- GCN pipeline ----
    k_xform1<<<(n + 31) / 32, 256, 0, stream>>>(x, W1, dinv, (float4*)g1, n);
    k_agg32_mid<<<(n + 3) / 4, 256, 0, stream>>>(rowptr, rowend, csr_src, (const float4*)g1,
                                                 dinv, b1, W2, g2, n);
    k_agg3_final<<<(n + 3) / 4, 256, 0, stream>>>(rowptr, rowend, csr_src, g2, dinv, b2, out, n);
}

// Round 5
// 230.809 us; speedup vs baseline: 8.7623x; 1.1428x over previous
//
#include <hip/hip_runtime.h>

// Problem constants (fixed by the reference setup_inputs).
static constexpr int NN = 100000;   // nodes
static constexpr int NE = 3200000;  // edges

// Bucketed counting-sort parameters.
static constexpr int BKT_SHIFT = 9;                       // 512 nodes per bucket
static constexpr int BKT_NODES = 1 << BKT_SHIFT;          // 512
static constexpr int NBUCK = (NN + BKT_NODES - 1) >> BKT_SHIFT;  // 196
static constexpr int P1_BLOCKS = 256;
static constexpr int EPB = NE / P1_BLOCKS;                // 12500 edges per phase-1 block (exact)
static constexpr int EPT = (EPB + 255) / 256;             // 49 edges per thread
static constexpr int HTOT = NBUCK * P1_BLOCKS;            // 50176 histogram cells
static constexpr int H2_T = 1024;
static constexpr int H2_C = HTOT / H2_T;                  // 49 (exact)

// ---------------- phase 1a: per-block bucket histograms (LDS, no global atomics) ----------------

__global__ void k_hist(const int* __restrict__ dst, int* __restrict__ bh) {
    __shared__ int hist[256];
    int t = threadIdx.x, blk = blockIdx.x;
    hist[t] = 0;
    __syncthreads();
    int base = blk * EPB;
#pragma unroll
    for (int j = 0; j < EPT; ++j) {
        int o = j * 256 + t;
        if (o < EPB) atomicAdd(&hist[dst[base + o] >> BKT_SHIFT], 1);
    }
    __syncthreads();
    if (t < NBUCK) bh[t * P1_BLOCKS + blk] = hist[t];  // bucket-major
}

// ---------------- phase 1b: exclusive scan of all 50176 cells, in place (single block) --------

__global__ void k_hscan(int* __restrict__ bh) {
    __shared__ int s[H2_T];
    int t = threadIdx.x;
    int base = t * H2_C;
    int sum = 0;
#pragma unroll
    for (int j = 0; j < H2_C; ++j) sum += bh[base + j];
    s[t] = sum;
    __syncthreads();
    for (int off = 1; off < H2_T; off <<= 1) {
        int add = (t >= off) ? s[t - off] : 0;
        __syncthreads();
        s[t] += add;
        __syncthreads();
    }
    int run = s[t] - sum;  // exclusive prefix of this thread's chunk
#pragma unroll
    for (int j = 0; j < H2_C; ++j) {
        int v = bh[base + j];
        bh[base + j] = run;
        run += v;
    }
}

// ---------------- phase 1c: scatter packed (src,dlocal) keys into bucket order ----------------

__global__ void k_bucket(const int* __restrict__ src, const int* __restrict__ dst,
                         const int* __restrict__ bh, int* __restrict__ keys) {
    __shared__ int cur[256];
    int t = threadIdx.x, blk = blockIdx.x;
    if (t < NBUCK) cur[t] = bh[t * P1_BLOCKS + blk];
    __syncthreads();
    int base = blk * EPB;
#pragma unroll
    for (int j = 0; j < EPT; ++j) {
        int o = j * 256 + t;
        if (o < EPB) {
            int d = dst[base + o];
            int b = d >> BKT_SHIFT;
            int pos = atomicAdd(&cur[b], 1);  // LDS atomic only
            keys[pos] = (src[base + o] << BKT_SHIFT) | (d & (BKT_NODES - 1));
        }
    }
}

// ---------------- phase 2: per-bucket exact CSR + rowptr/rowend/dinv/xd (LDS only) ---------------
// Also emits xd[node] = {x * dinv, pad} -- the only per-node data layer-1 aggregation needs,
// since (sum_e x[s]*dinv[s]) @ W1 == sum_e (x[s]@W1)*dinv[s]  (linearity).

__global__ void k_csr(const int* __restrict__ keys, const int* __restrict__ bh,
                      const float* __restrict__ x, int* __restrict__ csr_src,
                      int* __restrict__ rowptr, int* __restrict__ rowend,
                      float* __restrict__ dinv, float4* __restrict__ xd, int n) {
    __shared__ int cnt[BKT_NODES];
    __shared__ int s[BKT_NODES];
    __shared__ int cur[BKT_NODES];
    int t = threadIdx.x, b = blockIdx.x;
    int bstart = bh[b * P1_BLOCKS];
    int bend = (b + 1 < NBUCK) ? bh[(b + 1) * P1_BLOCKS] : NE;
    cnt[t] = 0;
    __syncthreads();
    for (int i = bstart + t; i < bend; i += BKT_NODES)
        atomicAdd(&cnt[keys[i] & (BKT_NODES - 1)], 1);
    __syncthreads();
    int c = cnt[t];
    s[t] = c;
    __syncthreads();
    for (int off = 1; off < BKT_NODES; off <<= 1) {
        int add = (t >= off) ? s[t - off] : 0;
        __syncthreads();
        s[t] += add;
        __syncthreads();
    }
    int rp = bstart + s[t] - c;  // exclusive
    cur[t] = rp;
    int node = b * BKT_NODES + t;
    if (node < n) {
        rowptr[node] = rp;
        rowend[node] = rp + c;
        float di = rsqrtf((float)c + 1.0f);  // +1 self-loop
        dinv[node] = di;
        xd[node] = make_float4(x[node * 3 + 0] * di, x[node * 3 + 1] * di,
                               x[node * 3 + 2] * di, 0.f);
    }
    __syncthreads();
    for (int i = bstart + t; i < bend; i += BKT_NODES) {
        int k = keys[i];
        int pos = atomicAdd(&cur[k & (BKT_NODES - 1)], 1);  // LDS atomic only
        csr_src[pos] = ((unsigned)k) >> BKT_SHIFT;
    }
}

// ---------------- fused layer-1 aggregation + full mid node pass ----------------
// One wave per node: a = sum_{in-edges} xd[src] + xd[self]  (3-dim!);
// h = relu(dinv * (a @ W1) + b1); g2 = (h @ W2) * dinv  (padded float4 store).

__global__ void k_agg1(const int* __restrict__ rowptr, const int* __restrict__ rowend,
                       const int* __restrict__ csr_src, const float4* __restrict__ xd,
                       const float* __restrict__ dinv, const float* __restrict__ W1,
                       const float* __restrict__ b1, const float* __restrict__ W2,
                       float4* __restrict__ g2, int n) {
    __shared__ float W1s[96];   // [3][32] row-major
    __shared__ float W2s[96];   // [32][3] row-major
    __shared__ float b1s[32];
    int tid = threadIdx.x;
    if (tid < 96) { W1s[tid] = W1[tid]; W2s[tid] = W2[tid]; }
    if (tid < 32) b1s[tid] = b1[tid];
    __syncthreads();

    int node = blockIdx.x * 4 + (tid >> 6);
    if (node >= n) return;
    int lane = tid & 63;
    int beg = rowptr[node], end = rowend[node];

    float a0 = 0.f, a1 = 0.f, a2 = 0.f;
    for (int i = beg + lane; i < end; i += 64) {
        float4 v = xd[csr_src[i]];
        a0 += v.x; a1 += v.y; a2 += v.z;
    }
    for (int off = 32; off >= 1; off >>= 1) {
        a0 += __shfl_xor(a0, off, 64);
        a1 += __shfl_xor(a1, off, 64);
        a2 += __shfl_xor(a2, off, 64);
    }
    float4 self = xd[node];  // self-loop term (already * dinv[node])
    a0 += self.x; a1 += self.y; a2 += self.z;

    float di = dinv[node];
    float p0 = 0.f, p1 = 0.f, p2 = 0.f;
    if (lane < 32) {
        float h = fmaxf(di * (a0 * W1s[lane] + a1 * W1s[32 + lane] + a2 * W1s[64 + lane])
                        + b1s[lane], 0.f);
        p0 = h * W2s[lane * 3 + 0];
        p1 = h * W2s[lane * 3 + 1];
        p2 = h * W2s[lane * 3 + 2];
    }
    for (int off = 32; off >= 1; off >>= 1) {
        p0 += __shfl_xor(p0, off, 64);
        p1 += __shfl_xor(p1, off, 64);
        p2 += __shfl_xor(p2, off, 64);
    }
    if (lane == 0) g2[node] = make_float4(p0 * di, p1 * di, p2 * di, 0.f);
}

// ---------------- fused layer-2 aggregation + final ----------------

__global__ void k_agg2(const int* __restrict__ rowptr, const int* __restrict__ rowend,
                       const int* __restrict__ csr_src, const float4* __restrict__ g2,
                       const float* __restrict__ dinv, const float* __restrict__ b2,
                       float* __restrict__ out, int n) {
    int tid = threadIdx.x;
    int node = blockIdx.x * 4 + (tid >> 6);
    if (node >= n) return;
    int lane = tid & 63;
    int beg = rowptr[node], end = rowend[node];

    float a0 = 0.f, a1 = 0.f, a2 = 0.f;
    for (int i = beg + lane; i < end; i += 64) {
        float4 v = g2[csr_src[i]];
        a0 += v.x; a1 += v.y; a2 += v.z;
    }
    for (int off = 32; off >= 1; off >>= 1) {
        a0 += __shfl_xor(a0, off, 64);
        a1 += __shfl_xor(a1, off, 64);
        a2 += __shfl_xor(a2, off, 64);
    }
    if (lane == 0) {
        float4 self = g2[node];
        float di = dinv[node];
        out[node * 3 + 0] = di * (a0 + self.x) + b2[0];
        out[node * 3 + 1] = di * (a1 + self.y) + b2[1];
        out[node * 3 + 2] = di * (a2 + self.z) + b2[2];
    }
}

extern "C" void kernel_launch(void* const* d_in, const int* in_sizes, int n_in,
                              void* d_out, int out_size, void* d_ws, size_t ws_size,
                              hipStream_t stream) {
    const float* x   = (const float*)d_in[0];  // [N,3]
    const int* ei    = (const int*)d_in[1];    // [2,E] int32: src = ei[0:E], dst = ei[E:2E]
    const float* W1  = (const float*)d_in[2];  // [3,32]
    const float* b1  = (const float*)d_in[3];  // [32]
    const float* W2  = (const float*)d_in[4];  // [32,3]
    const float* b2  = (const float*)d_in[5];  // [3]
    float* out       = (float*)d_out;          // [N,3]

    const int n = NN;
    const int* src = ei;
    const int* dst = ei + NE;

    // Workspace layout (4-byte units):
    //   [0]      keys (NE ints) during build; g2 (4n floats) aliased here afterwards
    //   [NE]     csr_src (NE ints)
    //   [2NE]    dinv (n) | rowptr (n) | rowend (n) | xd (4n floats) | bh (HTOT)
    int* wsi      = (int*)d_ws;
    int* keys     = wsi;                       // dead after k_csr
    float4* g2    = (float4*)wsi;              // aliases keys (4n = 1.6 MB << NE)
    int* csr_src  = wsi + (size_t)NE;
    float* dinv   = (float*)(wsi + (size_t)2 * NE);
    int* rowptr   = (int*)(dinv + n);
    int* rowend   = rowptr + n;
    float4* xd    = (float4*)(rowend + n);
    int* bh       = (int*)(rowend + n + (size_t)4 * n);

    // ---- atomic-free CSR build (+ dinv, xd) ----
    k_hist<<<P1_BLOCKS, 256, 0, stream>>>(dst, bh);
    k_hscan<<<1, H2_T, 0, stream>>>(bh);
    k_bucket<<<P1_BLOCKS, 256, 0, stream>>>(src, dst, bh, keys);
    k_csr<<<NBUCK, BKT_NODES, 0, stream>>>(keys, bh, x, csr_src, rowptr, rowend, dinv, xd, n);

    // ---- fused GCN pipeline (3-feature aggregations only) ----
    k_agg1<<<(n + 3) / 4, 256, 0, stream>>>(rowptr, rowend, csr_src, xd, dinv, W1, b1, W2, g2, n);
    k_agg2<<<(n + 3) / 4, 256, 0, stream>>>(rowptr, rowend, csr_src, g2, dinv, b2, out, n);
}